// Round 10
// baseline (238.898 us; speedup 1.0000x reference)
//
#include <hip/hip_runtime.h>
#include <hip/hip_fp16.h>

// CTC-like forward scan. R21 = R20's two wings INTERLEAVED IN ONE WAVE.
//   out = e_sl^T B_T...B_1 e_0,  B_t lower-bidiagonal (diag S_t, sub V_t).
// Evidence: solo wing = 109 cy/step but only ~40 cy real VALU issue (~20
// instrs x 2cy; 4cy-formula VALUBusy matches static count) => ~60% per-wave
// stall its own stream can't fill. R18: a second WAVE on the SIMD fills it
// poorly (1.22x, 8 waves/CU shared-resource). Here the second INDEPENDENT
// stream lives in the SAME wave: fwd chain (rows 0..2047) + bwd chain (rows
// 4095..2048) of one batch, register-independent, shared ctrl, compiler
// interleaves at instruction granularity. Junction becomes wave-local =>
// join kernel + jbuf eliminated (2 launches; the total-vs-scan gap showed
// ~10us per launch). 64 blocks x 64 threads, two 8KB rings, interleaved
// gload streams with vmcnt(6) (oldest f,b pair resident), in-kernel 513-LSE.
// Chain math byte-identical to R20 wings (passed, absmax 0.0); two logs
// accumulators summed at end (same summation order as R19/R20).
// Validation: step-pair <=115 cy => stall-filling works; >=180 => shared
// per-CU resource binds, line closed.

#define TT 4096
#define BB 64
#define PP 512
#define LN2F 0.69314718055994531f
#define LOG2E 1.44269504088896341f

typedef unsigned u32x4 __attribute__((ext_vector_type(4)));

__device__ __forceinline__ unsigned f16_bits(float f) {
    return (unsigned)__half_as_ushort(__float2half(f));   // v_cvt_f16_f32, RNE
}

// prepass: x[t][b][5] -> xq[b*4096+t] = {f16W0|W1, f16W2|W3, f32 x4, 0}
__global__ __launch_bounds__(256, 1)
void ctc_prepass(const float* __restrict__ x, u32x4* __restrict__ xq) {
    int j = blockIdx.x * 256 + threadIdx.x;
    int b = j >> 12, t = j & 4095;
    const float* r = x + (size_t)(t * 64 + b) * 5;
    float x0 = r[0], x1 = r[1], x2 = r[2], x3 = r[3], x4 = r[4];
    float w0 = fminf(__expf(x0 - x4), 65000.0f);   // clamp: f16 inf insurance
    float w1 = fminf(__expf(x1 - x4), 65000.0f);
    float w2 = fminf(__expf(x2 - x4), 65000.0f);
    float w3 = fminf(__expf(x3 - x4), 65000.0f);
    u32x4 o;
    o[0] = f16_bits(w0) | (f16_bits(w1) << 16);
    o[1] = f16_bits(w2) | (f16_bits(w3) << 16);
    o[2] = __float_as_uint(x4);
    o[3] = 0u;
    xq[j] = o;
}

__device__ __forceinline__ void gload_lds16(const void* g, void* l) {
    auto gp = (const __attribute__((address_space(1))) void*)(uintptr_t)g;
    auto lp = (__attribute__((address_space(3))) void*)(uintptr_t)l;
    __builtin_amdgcn_global_load_lds(gp, lp, 16, 0, 0);
}

// lane n <- lane n-1 (wave_shr:1); lane 0 keeps old (overridden).
__device__ __forceinline__ int shl1w_i(int s) {
    return __builtin_amdgcn_update_dpp(s, s, 0x138, 0xF, 0xF, false);
}
__device__ __forceinline__ float shl1w_f(float s) {
    return __int_as_float(shl1w_i(__float_as_int(s)));
}
// lane n <- lane n+1 (wave_shl:1); lane 63 keeps old (overridden).
__device__ __forceinline__ int sh1up_i(int s) {
    return __builtin_amdgcn_update_dpp(s, s, 0x130, 0xF, 0xF, false);
}
__device__ __forceinline__ float sh1up_f(float s) {
    return __int_as_float(sh1up_i(__float_as_int(s)));
}

// acc += s * f16(lo/hi of p)   -- one v_fma_mix_f32, f16 source in S1
#define FMA_MIX_LO(acc, s, p)                                              \
    asm("v_fma_mix_f32 %0, %1, %2, %0 op_sel:[0,0,0] op_sel_hi:[0,1,0]"    \
        : "+v"(acc) : "v"(s), "v"(p))
#define FMA_MIX_HI(acc, s, p)                                              \
    asm("v_fma_mix_f32 %0, %1, %2, %0 op_sel:[0,1,0] op_sel_hi:[0,1,0]"    \
        : "+v"(acc) : "v"(s), "v"(p))

__global__ __launch_bounds__(64, 1)
void ctc_scan(const u32x4* __restrict__ xq, const int* __restrict__ seqs,
              const int* __restrict__ seqlens, float* __restrict__ out) {
    __shared__ __align__(16) u32x4 ringF[512];     // 8 KB each
    __shared__ __align__(16) u32x4 ringB[512];
    __shared__ float gF[PP + 1];
    __shared__ float gB[PP + 1];

    const int b = blockIdx.x;
    const int l = threadIdx.x;                     // 0..63
    const bool lane0 = (l == 0);
    const bool lane63 = (l == 63);
    const int sl = seqlens[b];
    const bool b512 = (sl == PP);

    // per-lane v_perm byte controls -- shared by both chains.
    unsigned ctrl[4];
#pragma unroll
    for (int k = 0; k < 4; ++k) {
        unsigned i0 = (unsigned)seqs[b * PP + 8 * l + 2 * k];
        unsigned i1 = (unsigned)seqs[b * PP + 8 * l + 2 * k + 1];
        ctrl[k] = (2 * i0) | ((2 * i0 + 1) << 8) | ((2 * i1) << 16) | ((2 * i1 + 1) << 24);
    }

    const u32x4* gsrc = xq + (size_t)b * 4096;     // row t at gsrc[t]

    // ---- interleaved initial staging: f0,b0,f1,b1,... (8 in flight) ----
#pragma unroll
    for (int c0 = 0; c0 < 4; ++c0) {
        gload_lds16(gsrc + c0 * 64 + l, &ringF[c0 * 64 + l]);
        const int cp = 63 - c0;
        gload_lds16(gsrc + cp * 64 + l, &ringB[(cp & 7) * 64 + l]);
    }
    asm volatile("s_waitcnt vmcnt(6)" ::: "memory");   // oldest f,b pair resident

    float Ff[8], Fb[8];
#pragma unroll
    for (int i = 0; i < 8; ++i) Ff[i] = 0.0f;
#pragma unroll
    for (int k = 0; k < 8; ++k) Fb[k] = (8 * l + k == sl) ? 1.0f : 0.0f;
    int Mf = 0, Mb = 0;
    float logsF = 0.0f, logsB = 0.0f;

    u32x4 fA[8], fB[8], bA[8], bB[8];
#pragma unroll
    for (int i = 0; i < 8; ++i) { fA[i] = ringF[i]; bA[i] = ringB[511 - i]; }
    int nrowF = 8;                                 // next fwd window base row
    int nbaseB = 4087;                             // next bwd window top row

    auto win = [&](u32x4 (&curF)[8], u32x4 (&nxtF)[8],
                   u32x4 (&curB)[8], u32x4 (&nxtB)[8]) {
        // ---- next-window loads, both chains ----
        const int rbF = nrowF & 511;
        nrowF += 8;
#pragma unroll
        for (int i = 0; i < 8; ++i) nxtF[i] = ringF[rbF + i];
        const int rb7 = (nbaseB & 511) - 7;        // nbase mod 8 == 7 always
        nbaseB -= 8;
#pragma unroll
        for (int i = 0; i < 8; ++i) nxtB[i] = ringB[rb7 + (7 - i)];
        asm volatile("" ::: "memory");

        // ---- fwd bookkeeping ----
        float mf = Ff[0];
#pragma unroll
        for (int i = 1; i < 8; ++i) mf = fmaxf(mf, Ff[i]);
        int e2f = ((__float_as_int(mf) >> 23) & 0xFF) - 127;
        e2f = (mf > 0.0f) ? e2f : 0;
        const int Mpf = Mf + e2f;
        const int Mlpf = shl1w_i(Mpf);
        int dlf = (lane0 ? 0 : Mlpf) - Mpf;
        int dlcf = dlf > 0 ? dlf : 0;
        const int Mnf = Mpf + dlcf;
        const int shf = Mnf - Mf;
#pragma unroll
        for (int i = 0; i < 8; ++i) Ff[i] = ldexpf(Ff[i], -shf);
        Mf = Mnf;
        int dnf = Mlpf - Mf; dnf = dnf > 0 ? 0 : dnf;
        const float sAxf  = lane0 ? 0.0f : ldexpf(1.0f, dnf);
        const float cfinf = lane0 ? ldexpf(1.0f, -Mf) : 0.0f;

        // ---- bwd bookkeeping ----
        float mb = Fb[0];
#pragma unroll
        for (int i = 1; i < 8; ++i) mb = fmaxf(mb, Fb[i]);
        int e2b = ((__float_as_int(mb) >> 23) & 0xFF) - 127;
        e2b = (mb > 0.0f) ? e2b : 0;
        const int Mpb = Mb + e2b;
        const int Mupb = sh1up_i(Mpb);
        int nbb = lane63 ? (b512 ? 0 : -1048576) : Mupb;
        int dlb = nbb - Mpb;
        int dlcb = dlb > 0 ? dlb : 0;
        const int Mnb = Mpb + dlcb;
        const int shb = Mnb - Mb;
#pragma unroll
        for (int i = 0; i < 8; ++i) Fb[i] = ldexpf(Fb[i], -shb);
        Mb = Mnb;
        int dnb = Mupb - Mb; dnb = dnb > 0 ? 0 : dnb;
        const float sAxb  = lane63 ? 0.0f : ldexpf(1.0f, dnb);
        const float cfinb = (lane63 && b512) ? ldexpf(1.0f, -Mb) : 0.0f;

        // ---- 8 step-pairs: fwd step + bwd step (register-independent) ----
#pragma unroll
        for (int u = 0; u < 8; ++u) {
            {   // fwd step on curF[u]
                const u32x4 row = curF[u];
                logsF += __uint_as_float(row[2]);
                unsigned p0 = __builtin_amdgcn_perm(row[1], row[0], ctrl[0]);
                unsigned p1 = __builtin_amdgcn_perm(row[1], row[0], ctrl[1]);
                unsigned p2 = __builtin_amdgcn_perm(row[1], row[0], ctrl[2]);
                unsigned p3 = __builtin_amdgcn_perm(row[1], row[0], ctrl[3]);
                const float Flr = shl1w_f(Ff[7]);
                const float fin = fmaf(Flr, sAxf, cfinf);
                FMA_MIX_HI(Ff[7], Ff[6], p3);
                FMA_MIX_LO(Ff[6], Ff[5], p3);
                FMA_MIX_HI(Ff[5], Ff[4], p2);
                FMA_MIX_LO(Ff[4], Ff[3], p2);
                FMA_MIX_HI(Ff[3], Ff[2], p1);
                FMA_MIX_LO(Ff[2], Ff[1], p1);
                FMA_MIX_HI(Ff[1], Ff[0], p0);
                FMA_MIX_LO(Ff[0], fin,  p0);
            }
            {   // bwd step on curB[u]
                const u32x4 row = curB[u];
                logsB += __uint_as_float(row[2]);
                unsigned p0 = __builtin_amdgcn_perm(row[1], row[0], ctrl[0]);
                unsigned p1 = __builtin_amdgcn_perm(row[1], row[0], ctrl[1]);
                unsigned p2 = __builtin_amdgcn_perm(row[1], row[0], ctrl[2]);
                unsigned p3 = __builtin_amdgcn_perm(row[1], row[0], ctrl[3]);
                const float Bur = sh1up_f(Fb[0]);
                const float fin = fmaf(Bur, sAxb, cfinb);
                FMA_MIX_LO(Fb[0], Fb[1], p0);
                FMA_MIX_HI(Fb[1], Fb[2], p0);
                FMA_MIX_LO(Fb[2], Fb[3], p1);
                FMA_MIX_HI(Fb[3], Fb[4], p1);
                FMA_MIX_LO(Fb[4], Fb[5], p2);
                FMA_MIX_HI(Fb[5], Fb[6], p2);
                FMA_MIX_LO(Fb[6], Fb[7], p3);
                FMA_MIX_HI(Fb[7], fin,  p3);
            }
        }
    };

#pragma unroll 1
    for (int c = 0; c < 32; ++c) {
        int csF = (c + 4 > 31) ? 31 : (c + 4);
        gload_lds16(gsrc + csF * 64 + l, &ringF[((c + 4) & 7) * 64 + l]);
        int cpB = 59 - c; cpB = cpB < 32 ? 32 : cpB;
        gload_lds16(gsrc + cpB * 64 + l, &ringB[(cpB & 7) * 64 + l]);
        asm volatile("s_waitcnt vmcnt(6)" ::: "memory");   // f(c+1), b(c+1) resident
#pragma unroll 1
        for (int pr = 0; pr < 4; ++pr) {
            win(fA, fB, bA, bB);
            win(fB, fA, bB, bA);
        }
    }

    // ---- wave-local junction: log2 tables + 513-entry LSE ----
#pragma unroll
    for (int i = 0; i < 8; ++i) {
        float v = fmaxf(Ff[i] * 16777216.0f, 1e-38f);
        gF[8 * l + 1 + i] = __log2f(v) - 24.0f + (float)Mf;
    }
#pragma unroll
    for (int k = 0; k < 8; ++k) {
        float v = fmaxf(Fb[k] * 16777216.0f, 1e-38f);
        gB[8 * l + k] = __log2f(v) - 24.0f + (float)Mb;
    }
    if (lane0) { gF[0] = 0.0f; gB[PP] = b512 ? 0.0f : -1e30f; }
    asm volatile("s_waitcnt lgkmcnt(0)" ::: "memory");   // single wave: no barrier
    __builtin_amdgcn_sched_barrier(0);

    float smax = -3.0e38f;
#pragma unroll
    for (int k = 0; k < 9; ++k) {
        const int p = l + (k << 6);
        if (p <= PP) smax = fmaxf(smax, gF[p] + gB[p]);
    }
#pragma unroll
    for (int off = 32; off >= 1; off >>= 1)
        smax = fmaxf(smax, __shfl_xor(smax, off));
    float ssum = 0.0f;
#pragma unroll
    for (int k = 0; k < 9; ++k) {
        const int p = l + (k << 6);
        if (p <= PP) ssum += exp2f((gF[p] + gB[p]) - smax);
    }
#pragma unroll
    for (int off = 32; off >= 1; off >>= 1)
        ssum += __shfl_xor(ssum, off);
    if (lane0) {
        const float lgS = (logsF + logsB) * LOG2E;
        out[b] = -((smax + __log2f(ssum)) + lgS) * LN2F / (float)TT;
    }
}

extern "C" void kernel_launch(void* const* d_in, const int* in_sizes, int n_in,
                              void* d_out, int out_size, void* d_ws, size_t ws_size,
                              hipStream_t stream) {
    const float* x       = (const float*)d_in[0];
    const int*   seqs    = (const int*)d_in[1];
    const int*   seqlens = (const int*)d_in[2];
    float*       out     = (float*)d_out;
    u32x4*       xq      = (u32x4*)d_ws;           // TT*BB rows x 16 B = 4 MB

    ctc_prepass<<<(TT * BB) / 256, 256, 0, stream>>>(x, xq);
    ctc_scan<<<BB, 64, 0, stream>>>(xq, seqs, seqlens, out);
}

// Round 11
// 166.395 us; speedup vs baseline: 1.4357x; 1.4357x over previous
//
#include <hip/hip_runtime.h>
#include <hip/hip_fp16.h>

// CTC-like forward scan. R22 = R20 collapsed to ONE kernel (+256B memset).
//   out = e_sl^T B_T...B_1 e_0,  B_t lower-bidiagonal (diag S_t, sub V_t).
// Model is now pinned (R18/R21): each step issues ~40 slots at 2cy, ~75%
// issue-occupancy in every config => ~109-122 cy/step is structural. The
// remaining fat was ~50-60us of fixed multi-kernel dispatch overhead (stable
// across all rounds). This round:
//  1) prepass folded into the wings: per 64-row chunk each lane asm-loads its
//     row's 5 floats from x one chunk ahead (named regs, vmcnt+sched_barrier
//     fences per rule #18), computes W=exp(xi-x4) clamped + f16 RNE pack
//     (identical numerics to the old prepass), ds_writes the packed row.
//     xq workspace + prepass kernel + global_load_lds pipeline deleted.
//  2) join folded into the fwd wing: bwd block writes its 513-entry log2
//     table + scale to jbuf, threadfence + agent release-store flag; fwd
//     lane0 acquire-spins (wings equal length => ~0-3us), then wave-local
//     LSE. 128 blocks <= 256 CUs => all co-resident => no deadlock.
// Wing chain math byte-identical to R19/R20 (passed, absmax 0.0): G-space,
// f16 W via v_perm + forced v_fma_mix_f32, renorm every 8 steps, down-only
// alignment, DPP boundary, logs = sum x4.

#define TT 4096
#define BB 64
#define PP 512
#define LN2F 0.69314718055994531f
#define LOG2E 1.44269504088896341f
#define JSTR 520   // per-batch floats in jbuf: [0..512]=log2 gb, [514]=lgSB

typedef unsigned u32x4 __attribute__((ext_vector_type(4)));

__device__ __forceinline__ unsigned f16_bits(float f) {
    return (unsigned)__half_as_ushort(__float2half(f));   // v_cvt_f16_f32, RNE
}

// lane n <- lane n-1 (wave_shr:1); lane 0 keeps old (overridden).
__device__ __forceinline__ int shl1w_i(int s) {
    return __builtin_amdgcn_update_dpp(s, s, 0x138, 0xF, 0xF, false);
}
__device__ __forceinline__ float shl1w_f(float s) {
    return __int_as_float(shl1w_i(__float_as_int(s)));
}
// lane n <- lane n+1 (wave_shl:1); lane 63 keeps old (overridden).
__device__ __forceinline__ int sh1up_i(int s) {
    return __builtin_amdgcn_update_dpp(s, s, 0x130, 0xF, 0xF, false);
}
__device__ __forceinline__ float sh1up_f(float s) {
    return __int_as_float(sh1up_i(__float_as_int(s)));
}

// acc += s * f16(lo/hi of p)   -- one v_fma_mix_f32, f16 source in S1
#define FMA_MIX_LO(acc, s, p)                                              \
    asm("v_fma_mix_f32 %0, %1, %2, %0 op_sel:[0,0,0] op_sel_hi:[0,1,0]"    \
        : "+v"(acc) : "v"(s), "v"(p))
#define FMA_MIX_HI(acc, s, p)                                              \
    asm("v_fma_mix_f32 %0, %1, %2, %0 op_sel:[0,1,0] op_sel_hi:[0,1,0]"    \
        : "+v"(acc) : "v"(s), "v"(p))

// 5 dword loads of one x row into named regs (issued early; cannot be sunk).
#define XLOAD(r0, r1, r2, r3, r4, ptr)                                     \
    asm volatile(                                                          \
        "global_load_dword %0, %5, off\n\t"                                \
        "global_load_dword %1, %5, off offset:4\n\t"                       \
        "global_load_dword %2, %5, off offset:8\n\t"                       \
        "global_load_dword %3, %5, off offset:12\n\t"                      \
        "global_load_dword %4, %5, off offset:16"                          \
        : "=&v"(r0), "=&v"(r1), "=&v"(r2), "=&v"(r3), "=&v"(r4)            \
        : "v"(ptr) : "memory")

// exp+clamp+f16-pack one row from regs, ds_write to ring slot (par).
#define PACK_ROW(par)                                                      \
    do {                                                                   \
        float e0 = fminf(__expf(xr0 - xr4), 65000.0f);                     \
        float e1 = fminf(__expf(xr1 - xr4), 65000.0f);                     \
        float e2 = fminf(__expf(xr2 - xr4), 65000.0f);                     \
        float e3 = fminf(__expf(xr3 - xr4), 65000.0f);                     \
        u32x4 o;                                                           \
        o[0] = f16_bits(e0) | (f16_bits(e1) << 16);                        \
        o[1] = f16_bits(e2) | (f16_bits(e3) << 16);                        \
        o[2] = __float_as_uint(xr4);                                       \
        o[3] = 0u;                                                         \
        ring[(par) * 64 + l] = o;                                          \
    } while (0)

__global__ __launch_bounds__(64, 1)
void ctc_scan(const float* __restrict__ x, const int* __restrict__ seqs,
              const int* __restrict__ seqlens, float* __restrict__ jbuf,
              int* __restrict__ flags, float* __restrict__ out) {
    __shared__ __align__(16) u32x4 ring[128];      // 2 chunks x 64 rows, 2 KB
    __shared__ float gF[PP + 1];

    const int b = blockIdx.x >> 1;                 // batch
    const int w = blockIdx.x & 1;                  // 0 = fwd, 1 = bwd
    const int l = threadIdx.x;                     // 0..63
    const bool lane0 = (l == 0);
    const bool lane63 = (l == 63);
    float* const jb = jbuf + (size_t)b * JSTR;

    // per-lane v_perm byte controls -- identical for both wings.
    unsigned ctrl[4];
#pragma unroll
    for (int k = 0; k < 4; ++k) {
        unsigned i0 = (unsigned)seqs[b * PP + 8 * l + 2 * k];
        unsigned i1 = (unsigned)seqs[b * PP + 8 * l + 2 * k + 1];
        ctrl[k] = (2 * i0) | ((2 * i0 + 1) << 8) | ((2 * i1) << 16) | ((2 * i1 + 1) << 24);
    }

    // x row (t,b) at x + (t*64+b)*5; this lane's chunk-row base:
    const float* const xb = x + (size_t)b * 5 + (size_t)l * 320;

    float F[8];
    int M = 0;
    float logs = 0.0f;
    float xr0, xr1, xr2, xr3, xr4;                 // prefetched x row (asm-pinned)

    if (w == 0) {
        // ================= FORWARD: rows 0..2047 ==========================
#pragma unroll
        for (int i = 0; i < 8; ++i) F[i] = 0.0f;

        // prologue: stage chunk 0, issue chunk 1
        XLOAD(xr0, xr1, xr2, xr3, xr4, xb);
        asm volatile("s_waitcnt vmcnt(0)" ::: "memory");
        __builtin_amdgcn_sched_barrier(0);
        PACK_ROW(0);
        XLOAD(xr0, xr1, xr2, xr3, xr4, xb + 64 * 320);
        asm volatile("s_waitcnt lgkmcnt(0)" ::: "memory");
        __builtin_amdgcn_sched_barrier(0);

        u32x4 wA[8], wB[8];
#pragma unroll
        for (int i = 0; i < 8; ++i) wA[i] = ring[i];
        int nrowF = 8;

        auto fwin = [&](u32x4 (&cur)[8], u32x4 (&nxt)[8]) {
            const int rb = ((nrowF >> 6) & 1) * 64 + (nrowF & 63);
            nrowF += 8;
#pragma unroll
            for (int i = 0; i < 8; ++i) nxt[i] = ring[rb + i];
            asm volatile("" ::: "memory");

            float m = F[0];
#pragma unroll
            for (int i = 1; i < 8; ++i) m = fmaxf(m, F[i]);
            int e2 = ((__float_as_int(m) >> 23) & 0xFF) - 127;
            e2 = (m > 0.0f) ? e2 : 0;
            const int Mp = M + e2;
            const int Mlp = shl1w_i(Mp);
            int dl = (lane0 ? 0 : Mlp) - Mp;
            int dlc = dl > 0 ? dl : 0;
            const int Mnew = Mp + dlc;
            const int sh = Mnew - M;
#pragma unroll
            for (int i = 0; i < 8; ++i) F[i] = ldexpf(F[i], -sh);
            M = Mnew;
            int dn = Mlp - M; dn = dn > 0 ? 0 : dn;
            const float sAx  = lane0 ? 0.0f : ldexpf(1.0f, dn);
            const float cfin = lane0 ? ldexpf(1.0f, -M) : 0.0f;

#pragma unroll
            for (int u = 0; u < 8; ++u) {
                const u32x4 row = cur[u];
                logs += __uint_as_float(row[2]);
                unsigned p0 = __builtin_amdgcn_perm(row[1], row[0], ctrl[0]);
                unsigned p1 = __builtin_amdgcn_perm(row[1], row[0], ctrl[1]);
                unsigned p2 = __builtin_amdgcn_perm(row[1], row[0], ctrl[2]);
                unsigned p3 = __builtin_amdgcn_perm(row[1], row[0], ctrl[3]);
                const float Flr = shl1w_f(F[7]);
                const float fin = fmaf(Flr, sAx, cfin);
                FMA_MIX_HI(F[7], F[6], p3);
                FMA_MIX_LO(F[6], F[5], p3);
                FMA_MIX_HI(F[5], F[4], p2);
                FMA_MIX_LO(F[4], F[3], p2);
                FMA_MIX_HI(F[3], F[2], p1);
                FMA_MIX_LO(F[2], F[1], p1);
                FMA_MIX_HI(F[1], F[0], p0);
                FMA_MIX_LO(F[0], fin,  p0);
            }
        };

#pragma unroll 1
        for (int c = 0; c < 32; ++c) {
            if (c + 1 < 32) {
                asm volatile("s_waitcnt vmcnt(0)" ::: "memory");
                __builtin_amdgcn_sched_barrier(0);
                PACK_ROW((c + 1) & 1);
                if (c + 2 < 32)
                    XLOAD(xr0, xr1, xr2, xr3, xr4, xb + (size_t)(c + 2) * 64 * 320);
                asm volatile("s_waitcnt lgkmcnt(0)" ::: "memory");
                __builtin_amdgcn_sched_barrier(0);
            }
#pragma unroll 1
            for (int pr = 0; pr < 4; ++pr) { fwin(wA, wB); fwin(wB, wA); }
        }

        // ---- junction: gF table in LDS, spin on bwd flag, 513-entry LSE ----
#pragma unroll
        for (int i = 0; i < 8; ++i) {
            float v = fmaxf(F[i] * 16777216.0f, 1e-38f);
            gF[8 * l + 1 + i] = __log2f(v) - 24.0f + (float)M;
        }
        if (lane0) gF[0] = 0.0f;
        asm volatile("s_waitcnt lgkmcnt(0)" ::: "memory");
        __builtin_amdgcn_sched_barrier(0);
        const float lgSF = logs * LOG2E;

        if (lane0) {
            while (__hip_atomic_load(&flags[b], __ATOMIC_ACQUIRE,
                                     __HIP_MEMORY_SCOPE_AGENT) == 0)
                __builtin_amdgcn_s_sleep(8);
        }
        // reconverged: bwd data visible (acquire cache-inv is CU-wide)

        float smax = -3.0e38f;
#pragma unroll
        for (int k = 0; k < 9; ++k) {
            const int p = l + (k << 6);
            if (p <= PP) smax = fmaxf(smax, gF[p] + jb[p]);
        }
#pragma unroll
        for (int off = 32; off >= 1; off >>= 1)
            smax = fmaxf(smax, __shfl_xor(smax, off));
        float ssum = 0.0f;
#pragma unroll
        for (int k = 0; k < 9; ++k) {
            const int p = l + (k << 6);
            if (p <= PP) ssum += exp2f((gF[p] + jb[p]) - smax);
        }
#pragma unroll
        for (int off = 32; off >= 1; off >>= 1)
            ssum += __shfl_xor(ssum, off);
        if (lane0)
            out[b] = -((smax + __log2f(ssum)) + lgSF + jb[514]) * LN2F / (float)TT;
    } else {
        // ================= BACKWARD: rows 4095..2048 (mirror) =============
        const int sl = seqlens[b];
        const bool b512 = (sl == PP);
#pragma unroll
        for (int k = 0; k < 8; ++k) F[k] = (8 * l + k == sl) ? 1.0f : 0.0f;

        // prologue: stage chunk 63 (slot 1), issue chunk 62
        XLOAD(xr0, xr1, xr2, xr3, xr4, xb + (size_t)63 * 64 * 320);
        asm volatile("s_waitcnt vmcnt(0)" ::: "memory");
        __builtin_amdgcn_sched_barrier(0);
        PACK_ROW(1);                               // chunk 63 -> slot 63&1 = 1
        XLOAD(xr0, xr1, xr2, xr3, xr4, xb + (size_t)62 * 64 * 320);
        asm volatile("s_waitcnt lgkmcnt(0)" ::: "memory");
        __builtin_amdgcn_sched_barrier(0);

        u32x4 wA[8], wB[8];
#pragma unroll
        for (int i = 0; i < 8; ++i) wA[i] = ring[127 - i];  // rows 4095..4088
        int nbaseB = 4087;

        auto bwin = [&](u32x4 (&cur)[8], u32x4 (&nxt)[8]) {
            const int rb = ((nbaseB >> 6) & 1) * 64 + (nbaseB & 63);
            nbaseB -= 8;
#pragma unroll
            for (int i = 0; i < 8; ++i) nxt[i] = ring[rb - i];
            asm volatile("" ::: "memory");

            float m = F[0];
#pragma unroll
            for (int i = 1; i < 8; ++i) m = fmaxf(m, F[i]);
            int e2 = ((__float_as_int(m) >> 23) & 0xFF) - 127;
            e2 = (m > 0.0f) ? e2 : 0;
            const int Mp = M + e2;
            const int Mup = sh1up_i(Mp);
            int nb = lane63 ? (b512 ? 0 : -1048576) : Mup;
            int dl = nb - Mp;
            int dlc = dl > 0 ? dl : 0;
            const int Mnew = Mp + dlc;
            const int sh = Mnew - M;
#pragma unroll
            for (int i = 0; i < 8; ++i) F[i] = ldexpf(F[i], -sh);
            M = Mnew;
            int dn = Mup - M; dn = dn > 0 ? 0 : dn;
            const float sAx  = lane63 ? 0.0f : ldexpf(1.0f, dn);
            const float cfin = (lane63 && b512) ? ldexpf(1.0f, -M) : 0.0f;

#pragma unroll
            for (int u = 0; u < 8; ++u) {
                const u32x4 row = cur[u];
                logs += __uint_as_float(row[2]);
                unsigned p0 = __builtin_amdgcn_perm(row[1], row[0], ctrl[0]);
                unsigned p1 = __builtin_amdgcn_perm(row[1], row[0], ctrl[1]);
                unsigned p2 = __builtin_amdgcn_perm(row[1], row[0], ctrl[2]);
                unsigned p3 = __builtin_amdgcn_perm(row[1], row[0], ctrl[3]);
                const float Bur = sh1up_f(F[0]);
                const float fin = fmaf(Bur, sAx, cfin);
                FMA_MIX_LO(F[0], F[1], p0);
                FMA_MIX_HI(F[1], F[2], p0);
                FMA_MIX_LO(F[2], F[3], p1);
                FMA_MIX_HI(F[3], F[4], p1);
                FMA_MIX_LO(F[4], F[5], p2);
                FMA_MIX_HI(F[5], F[6], p2);
                FMA_MIX_LO(F[6], F[7], p3);
                FMA_MIX_HI(F[7], fin,  p3);
            }
        };

#pragma unroll 1
        for (int c = 0; c < 32; ++c) {
            if (c + 1 < 32) {
                asm volatile("s_waitcnt vmcnt(0)" ::: "memory");
                __builtin_amdgcn_sched_barrier(0);
                PACK_ROW((62 - c) & 1);            // chunk 62-c
                if (c + 2 < 32)
                    XLOAD(xr0, xr1, xr2, xr3, xr4, xb + (size_t)(61 - c) * 64 * 320);
                asm volatile("s_waitcnt lgkmcnt(0)" ::: "memory");
                __builtin_amdgcn_sched_barrier(0);
            }
#pragma unroll 1
            for (int pr = 0; pr < 4; ++pr) { bwin(wA, wB); bwin(wB, wA); }
        }

        // ---- junction write: jb[p] = log2 gb[p] + Mb; publish + flag ----
#pragma unroll
        for (int k = 0; k < 8; ++k) {
            float v = fmaxf(F[k] * 16777216.0f, 1e-38f);
            jb[8 * l + k] = __log2f(v) - 24.0f + (float)M;
        }
        if (lane0) { jb[512] = b512 ? 0.0f : -1e30f; jb[514] = logs * LOG2E; }
        __threadfence();                           // device-scope: drain + L2 wb
        if (lane0)
            __hip_atomic_store(&flags[b], 1, __ATOMIC_RELEASE,
                               __HIP_MEMORY_SCOPE_AGENT);
    }
}

extern "C" void kernel_launch(void* const* d_in, const int* in_sizes, int n_in,
                              void* d_out, int out_size, void* d_ws, size_t ws_size,
                              hipStream_t stream) {
    const float* x       = (const float*)d_in[0];
    const int*   seqs    = (const int*)d_in[1];
    const int*   seqlens = (const int*)d_in[2];
    float*       out     = (float*)d_out;
    float*       jbuf    = (float*)d_ws;                          // 64*520 f32
    int*         flags   = (int*)((char*)d_ws + BB * JSTR * 4);   // 64 ints

    hipMemsetAsync(flags, 0, BB * sizeof(int), stream);
    ctc_scan<<<BB * 2, 64, 0, stream>>>(x, seqs, seqlens, jbuf, flags, out);
}

// Round 16
// 164.654 us; speedup vs baseline: 1.4509x; 1.0106x over previous
//
#include <hip/hip_runtime.h>
#include <hip/hip_fp16.h>

// CTC-like forward scan. R27 = R19 VERBATIM (session-best verified: 164.0us,
// absmax 0.0). Banking the best known-good kernel after the slim-cut arc
// (R23-R26) produced four consecutive non-passing rounds.
//   out = e_sl^T B_T...B_1 e_0,  B_t lower-bidiagonal (diag S_t, sub V_t).
// Post-mortem of the arc: R26 (logs-at-pack + period-16 under provably-sound
// stream-ordered sync) still failed inf => the R25 "junction race" theory is
// dead; the logs-at-pack transformation itself (algebraically null) breaks
// under some unidentified codegen interaction, and period-16 was never
// exonerated. All passing binaries share: in-loop logs, renorm period 8.
// Structure: prepass (x -> xq[b][t] = {f16 W0..W3, f32 x4}) + one scan
// kernel, BB blocks x 128 threads: wave 0 = fwd chain rows 0..2047 from
// G[0]=1 boundary; wave 1 = bwd chain rows 4095..2048 from e_sl; both
// G-space (W = exp(xi-x4), prod S recovered as sum x4), f16 W via v_perm +
// forced v_fma_mix_f32, renorm every 8 steps, down-only frame alignment,
// DPP boundary pass, per-wave global_load_lds staging rings (vmcnt(3)),
// wave-local 513-entry LSE junction after one __syncthreads.
// Perf model (pinned R14/R18/R20/R21): ~20 VALU slots/step x ~4cy pipe
// occupancy, +20% co-residency contention => ~112us scan; ~55us fixed
// harness overhead (kernel-count invariant, R20 vs R22).

#define TT 4096
#define BB 64
#define PP 512
#define LN2F 0.69314718055994531f
#define LOG2E 1.44269504088896341f

typedef unsigned u32x4 __attribute__((ext_vector_type(4)));

__device__ __forceinline__ unsigned f16_bits(float f) {
    return (unsigned)__half_as_ushort(__float2half(f));   // v_cvt_f16_f32, RNE
}

// prepass: x[t][b][5] -> xq[b*4096+t] = {f16W0|W1, f16W2|W3, f32 x4, 0}
__global__ __launch_bounds__(256, 1)
void ctc_prepass(const float* __restrict__ x, u32x4* __restrict__ xq) {
    int j = blockIdx.x * 256 + threadIdx.x;
    int b = j >> 12, t = j & 4095;
    const float* r = x + (size_t)(t * 64 + b) * 5;
    float x0 = r[0], x1 = r[1], x2 = r[2], x3 = r[3], x4 = r[4];
    float w0 = fminf(__expf(x0 - x4), 65000.0f);   // clamp: f16 inf insurance
    float w1 = fminf(__expf(x1 - x4), 65000.0f);
    float w2 = fminf(__expf(x2 - x4), 65000.0f);
    float w3 = fminf(__expf(x3 - x4), 65000.0f);
    u32x4 o;
    o[0] = f16_bits(w0) | (f16_bits(w1) << 16);
    o[1] = f16_bits(w2) | (f16_bits(w3) << 16);
    o[2] = __float_as_uint(x4);
    o[3] = 0u;
    xq[j] = o;
}

__device__ __forceinline__ void gload_lds16(const void* g, void* l) {
    auto gp = (const __attribute__((address_space(1))) void*)(uintptr_t)g;
    auto lp = (__attribute__((address_space(3))) void*)(uintptr_t)l;
    __builtin_amdgcn_global_load_lds(gp, lp, 16, 0, 0);
}

// lane n <- lane n-1 (wave_shr:1); lane 0 keeps old (overridden).
__device__ __forceinline__ int shl1w_i(int s) {
    return __builtin_amdgcn_update_dpp(s, s, 0x138, 0xF, 0xF, false);
}
__device__ __forceinline__ float shl1w_f(float s) {
    return __int_as_float(shl1w_i(__float_as_int(s)));
}
// lane n <- lane n+1 (wave_shl:1); lane 63 keeps old (overridden).
__device__ __forceinline__ int sh1up_i(int s) {
    return __builtin_amdgcn_update_dpp(s, s, 0x130, 0xF, 0xF, false);
}
__device__ __forceinline__ float sh1up_f(float s) {
    return __int_as_float(sh1up_i(__float_as_int(s)));
}

// acc += s * f16(lo/hi of p)   -- one v_fma_mix_f32, f16 source in S1
#define FMA_MIX_LO(acc, s, p)                                              \
    asm("v_fma_mix_f32 %0, %1, %2, %0 op_sel:[0,0,0] op_sel_hi:[0,1,0]"    \
        : "+v"(acc) : "v"(s), "v"(p))
#define FMA_MIX_HI(acc, s, p)                                              \
    asm("v_fma_mix_f32 %0, %1, %2, %0 op_sel:[0,1,0] op_sel_hi:[0,1,0]"    \
        : "+v"(acc) : "v"(s), "v"(p))

__global__ __launch_bounds__(128, 1)
void ctc_scan(const u32x4* __restrict__ xq, const int* __restrict__ seqs,
              const int* __restrict__ seqlens, float* __restrict__ out) {
    __shared__ __align__(16) u32x4 ringF[512];     // 8 KB each
    __shared__ __align__(16) u32x4 ringB[512];
    __shared__ float garrF[PP + 1];
    __shared__ float garrB[PP + 1];
    __shared__ float lgSh[2];

    const int tid = threadIdx.x;
    const int w = tid >> 6;                        // 0 = fwd, 1 = bwd
    const int l = tid & 63;
    const int b = blockIdx.x;
    const bool lane0 = (l == 0);
    const bool lane63 = (l == 63);

    // per-lane v_perm byte controls -- IDENTICAL for fwd and bwd:
    // fwd lane l owns G[8l+1..8l+8] (W[8l+1+i] uses seqs[8l+i]);
    // bwd lane l owns gb[8l..8l+7]  (W[8l+k+1] uses seqs[8l+k]).
    unsigned ctrl[4];
#pragma unroll
    for (int k = 0; k < 4; ++k) {
        unsigned i0 = (unsigned)seqs[b * PP + 8 * l + 2 * k];
        unsigned i1 = (unsigned)seqs[b * PP + 8 * l + 2 * k + 1];
        ctrl[k] = (2 * i0) | ((2 * i0 + 1) << 8) | ((2 * i1) << 16) | ((2 * i1 + 1) << 24);
    }

    const u32x4* gsrc = xq + (size_t)b * 4096;     // row t at gsrc[t]

    float F[8];
    int M = 0;
    float logs = 0.0f;

    if (w == 0) {
        // ================= FORWARD: rows 0..2047 ==========================
#pragma unroll
        for (int i = 0; i < 8; ++i) F[i] = 0.0f;
#pragma unroll
        for (int c0 = 0; c0 < 4; ++c0)
            gload_lds16(gsrc + c0 * 64 + l, &ringF[c0 * 64 + l]);
        asm volatile("s_waitcnt vmcnt(3)" ::: "memory");

        u32x4 wA[8], wB[8];
#pragma unroll
        for (int i = 0; i < 8; ++i) wA[i] = ringF[i];
        int nrow = 8;

        auto fwin = [&](u32x4 (&cur)[8], u32x4 (&nxt)[8]) {
            const int rb = nrow & 511;
            nrow += 8;
#pragma unroll
            for (int i = 0; i < 8; ++i) nxt[i] = ringF[rb + i];
            asm volatile("" ::: "memory");

            float m = F[0];
#pragma unroll
            for (int i = 1; i < 8; ++i) m = fmaxf(m, F[i]);
            int e2 = ((__float_as_int(m) >> 23) & 0xFF) - 127;
            e2 = (m > 0.0f) ? e2 : 0;
            const int Mp = M + e2;
            const int Mlp = shl1w_i(Mp);
            int dl = (lane0 ? 0 : Mlp) - Mp;
            int dlc = dl > 0 ? dl : 0;
            const int Mnew = Mp + dlc;
            const int sh = Mnew - M;
#pragma unroll
            for (int i = 0; i < 8; ++i) F[i] = ldexpf(F[i], -sh);
            M = Mnew;
            int dn = Mlp - M; dn = dn > 0 ? 0 : dn;
            const float sAx  = lane0 ? 0.0f : ldexpf(1.0f, dn);
            const float cfin = lane0 ? ldexpf(1.0f, -M) : 0.0f;

#pragma unroll
            for (int u = 0; u < 8; ++u) {
                const u32x4 row = cur[u];
                logs += __uint_as_float(row[2]);
                unsigned p0 = __builtin_amdgcn_perm(row[1], row[0], ctrl[0]);
                unsigned p1 = __builtin_amdgcn_perm(row[1], row[0], ctrl[1]);
                unsigned p2 = __builtin_amdgcn_perm(row[1], row[0], ctrl[2]);
                unsigned p3 = __builtin_amdgcn_perm(row[1], row[0], ctrl[3]);
                const float Flr = shl1w_f(F[7]);
                const float fin = fmaf(Flr, sAx, cfin);
                FMA_MIX_HI(F[7], F[6], p3);
                FMA_MIX_LO(F[6], F[5], p3);
                FMA_MIX_HI(F[5], F[4], p2);
                FMA_MIX_LO(F[4], F[3], p2);
                FMA_MIX_HI(F[3], F[2], p1);
                FMA_MIX_LO(F[2], F[1], p1);
                FMA_MIX_HI(F[1], F[0], p0);
                FMA_MIX_LO(F[0], fin,  p0);
            }
        };

#pragma unroll 1
        for (int c = 0; c < 32; ++c) {
            int cs = (c + 4 > 31) ? 31 : (c + 4);
            gload_lds16(gsrc + cs * 64 + l, &ringF[((c + 4) & 7) * 64 + l]);
            asm volatile("s_waitcnt vmcnt(3)" ::: "memory");
#pragma unroll 1
            for (int pr = 0; pr < 4; ++pr) { fwin(wA, wB); fwin(wB, wA); }
        }

        // junction write: garrF[p] = log2(gf[p]) + Mf ; garrF[0] = 0 (G[0]=1)
#pragma unroll
        for (int i = 0; i < 8; ++i) {
            float v = fmaxf(F[i] * 16777216.0f, 1e-38f);
            garrF[8 * l + 1 + i] = __log2f(v) - 24.0f + (float)M;
        }
        if (lane0) { garrF[0] = 0.0f; lgSh[0] = logs * LOG2E; }
    } else {
        // ================= BACKWARD: rows 4095..2048 (mirror) =============
        const int sl = seqlens[b];
        const bool b512 = (sl == PP);
#pragma unroll
        for (int k = 0; k < 8; ++k) F[k] = (8 * l + k == sl) ? 1.0f : 0.0f;
#pragma unroll
        for (int c0 = 0; c0 < 4; ++c0) {
            const int cp = 63 - c0;
            gload_lds16(gsrc + cp * 64 + l, &ringB[(cp & 7) * 64 + l]);
        }
        asm volatile("s_waitcnt vmcnt(3)" ::: "memory");   // chunk 63 resident

        u32x4 wA[8], wB[8];
#pragma unroll
        for (int i = 0; i < 8; ++i) wA[i] = ringB[511 - i];  // rows 4095..4088
        int nbase = 4095 - 8;                       // top row of next window

        auto bwin = [&](u32x4 (&cur)[8], u32x4 (&nxt)[8]) {
            const int rb = nbase & 511;
            nbase -= 8;
#pragma unroll
            for (int i = 0; i < 8; ++i) nxt[i] = ringB[(rb - i) & 511];
            asm volatile("" ::: "memory");

            float m = F[0];
#pragma unroll
            for (int i = 1; i < 8; ++i) m = fmaxf(m, F[i]);
            int e2 = ((__float_as_int(m) >> 23) & 0xFF) - 127;
            e2 = (m > 0.0f) ? e2 : 0;
            const int Mp = M + e2;
            const int Mup = sh1up_i(Mp);            // lane l+1's frame
            int nb = lane63 ? (b512 ? 0 : -1048576) : Mup;
            int dl = nb - Mp;
            int dlc = dl > 0 ? dl : 0;
            const int Mnew = Mp + dlc;
            const int sh = Mnew - M;
#pragma unroll
            for (int i = 0; i < 8; ++i) F[i] = ldexpf(F[i], -sh);
            M = Mnew;
            int dn = Mup - M; dn = dn > 0 ? 0 : dn;
            const float sAx  = lane63 ? 0.0f : ldexpf(1.0f, dn);
            const float cfin = (lane63 && b512) ? ldexpf(1.0f, -M) : 0.0f;

#pragma unroll
            for (int u = 0; u < 8; ++u) {
                const u32x4 row = cur[u];
                logs += __uint_as_float(row[2]);
                unsigned p0 = __builtin_amdgcn_perm(row[1], row[0], ctrl[0]);
                unsigned p1 = __builtin_amdgcn_perm(row[1], row[0], ctrl[1]);
                unsigned p2 = __builtin_amdgcn_perm(row[1], row[0], ctrl[2]);
                unsigned p3 = __builtin_amdgcn_perm(row[1], row[0], ctrl[3]);
                const float Bur = sh1up_f(F[0]);    // lane n <- n+1's gb-bottom
                const float fin = fmaf(Bur, sAx, cfin);
                // gb[p] += W[p+1]*gb[p+1], ascending (old upper values)
                FMA_MIX_LO(F[0], F[1], p0);
                FMA_MIX_HI(F[1], F[2], p0);
                FMA_MIX_LO(F[2], F[3], p1);
                FMA_MIX_HI(F[3], F[4], p1);
                FMA_MIX_LO(F[4], F[5], p2);
                FMA_MIX_HI(F[5], F[6], p2);
                FMA_MIX_LO(F[6], F[7], p3);
                FMA_MIX_HI(F[7], fin,  p3);
            }
        };

#pragma unroll 1
        for (int c = 0; c < 32; ++c) {
            int cp = 59 - c; cp = cp < 32 ? 32 : cp;
            gload_lds16(gsrc + cp * 64 + l, &ringB[(cp & 7) * 64 + l]);
            asm volatile("s_waitcnt vmcnt(3)" ::: "memory");
#pragma unroll 1
            for (int pr = 0; pr < 4; ++pr) { bwin(wA, wB); bwin(wB, wA); }
        }

        // junction write: garrB[p] = log2(gb[p]) + Mb ; garrB[512] = [sl==512]
#pragma unroll
        for (int k = 0; k < 8; ++k) {
            float v = fmaxf(F[k] * 16777216.0f, 1e-38f);
            garrB[8 * l + k] = __log2f(v) - 24.0f + (float)M;
        }
        if (lane0) { garrB[PP] = b512 ? 0.0f : -1e30f; lgSh[1] = logs * LOG2E; }
    }

    __syncthreads();

    // ---- junction: log2(out) = LSE2_p(garrF[p]+garrB[p]) + lgSF + lgSB ----
    if (w == 0) {
        float smax = -3.0e38f;
#pragma unroll
        for (int k = 0; k < 9; ++k) {
            const int p = l + (k << 6);
            if (p <= PP) smax = fmaxf(smax, garrF[p] + garrB[p]);
        }
#pragma unroll
        for (int off = 32; off >= 1; off >>= 1)
            smax = fmaxf(smax, __shfl_xor(smax, off));
        float ssum = 0.0f;
#pragma unroll
        for (int k = 0; k < 9; ++k) {
            const int p = l + (k << 6);
            if (p <= PP) ssum += exp2f((garrF[p] + garrB[p]) - smax);
        }
#pragma unroll
        for (int off = 32; off >= 1; off >>= 1)
            ssum += __shfl_xor(ssum, off);
        if (lane0)
            out[b] = -((smax + __log2f(ssum)) + lgSh[0] + lgSh[1]) * LN2F / (float)TT;
    }
}

extern "C" void kernel_launch(void* const* d_in, const int* in_sizes, int n_in,
                              void* d_out, int out_size, void* d_ws, size_t ws_size,
                              hipStream_t stream) {
    const float* x       = (const float*)d_in[0];
    const int*   seqs    = (const int*)d_in[1];
    const int*   seqlens = (const int*)d_in[2];
    float*       out     = (float*)d_out;
    u32x4*       xq      = (u32x4*)d_ws;           // TT*BB rows x 16 B = 4 MB

    ctc_prepass<<<(TT * BB) / 256, 256, 0, stream>>>(x, xq);
    ctc_scan<<<BB, 128, 0, stream>>>(xq, seqs, seqlens, out);
}